// Round 1
// baseline (352.209 us; speedup 1.0000x reference)
//
#include <hip/hip_runtime.h>
#include <stdint.h>
#include <stddef.h>

// ---------------------------------------------------------------------------
// AllModel: 4 GAE encoders, fp16 MFMA implementation.
//   step1: T1 = tanh(X  @ W1)^T        (stored [256][3072])
//   step2: Z1 = A @ T1^T               (stored [3072][256])
//   step3: T2 = tanh(Z1 @ W2)^T        (stored [128][3072])
//   step4: Z2 = A @ T2^T               (stored [3072][128])
//   step5: T3 = (Z2 @ W3)^T            (stored [128][3072], rows 64..127 zero)
//   step6: Z3 = A @ T3^T               (stored [3072][128], cols 64..127 zero)
//   step7: OUT = sigmoid(Z3 @ Z3^T)    (fp32 to d_out)
// All GEMMs: C = act(A_mat @ B_mat^T), A:[M][lda], B:[N][ldb] fp16 row-major.
// Encoders batched on blockIdx.z. Padded adjacency copies live in d_out
// (dead before step7 overwrites it).
// ---------------------------------------------------------------------------

typedef __attribute__((ext_vector_type(8))) _Float16 half8;
typedef __attribute__((ext_vector_type(4))) float f32x4;

#define PAD 3072
#define MR  3000

static __device__ __forceinline__ void async_cp16(const _Float16* g, _Float16* l) {
    __builtin_amdgcn_global_load_lds((const __attribute__((address_space(1))) void*)g,
                                     (__attribute__((address_space(3))) void*)l, 16, 0, 0);
}

// ---------------- prep kernels ----------------
struct Pad6 { const float* src[6]; _Float16* dst[6]; };

__global__ __launch_bounds__(256) void pad_cast6(Pad6 p) {
    const int z   = blockIdx.y;
    const int idx = blockIdx.x * 256 + threadIdx.x;   // one 8-elem chunk
    const int row = idx / 384;                        // 3072/8 = 384 chunks per row
    const int c0  = (idx - row * 384) * 8;
    half8 v;
    if (row < MR && c0 < MR) {
        const float* sp = p.src[z] + (size_t)row * MR + c0;
        #pragma unroll
        for (int j = 0; j < 8; ++j) v[j] = (_Float16)sp[j];
    } else {
        #pragma unroll
        for (int j = 0; j < 8; ++j) v[j] = (_Float16)0.f;
    }
    *(half8*)(p.dst[z] + (size_t)row * PAD + c0) = v;
}

struct Wt12 { const float* src[12]; _Float16* dst[12];
              int fi[12]; int fo[12]; int ldk[12]; int nr[12]; };

__global__ __launch_bounds__(256) void wt_cast12(Wt12 p) {
    const int z   = blockIdx.y;
    const int idx = blockIdx.x * 256 + threadIdx.x;
    const int ldk = p.ldk[z];
    if (idx >= p.nr[z] * ldk) return;
    const int r = idx / ldk;          // output row  = fan_out index
    const int k = idx - r * ldk;      // output col  = fan_in  index
    float v = 0.f;
    if (r < p.fo[z] && k < p.fi[z]) v = p.src[z][(size_t)k * p.fo[z] + r];
    p.dst[z][(size_t)r * ldk + k] = (_Float16)v;
}

// ---------------- GEMM: C = act(A @ B^T) ----------------
// ACT: 0 none, 1 tanh.  OMODE: 0 = fp16 C[m][n], 1 = fp16 C[n][m], 2 = fp32 sigmoid.
template<int ACT, int OMODE>
__global__ __launch_bounds__(256, 2)
void gemm_bt(const _Float16* __restrict__ Aall, size_t aStride, int aMask,
             const _Float16* __restrict__ Ball, size_t bStride,
             void* __restrict__ Call, size_t cStride,
             int M, int Ncols, int Kp, int lda, int ldb, int ldc)
{
    __shared__ _Float16 As[128 * 64];
    __shared__ _Float16 Bs[128 * 64];

    const int e  = blockIdx.z;
    const _Float16* A = Aall + (size_t)(e & aMask) * aStride;
    const _Float16* B = Ball + (size_t)e * bStride;
    const int tm = blockIdx.x * 128;
    const int tn = blockIdx.y * 128;
    const int t    = threadIdx.x;
    const int lane = t & 63;
    const int w    = t >> 6;
    const int wm   = (w >> 1) * 64;
    const int wn   = (w & 1) * 64;
    const int lr   = lane & 15;
    const int lg   = lane >> 4;

    f32x4 acc[4][4];
    const f32x4 zero = {0.f, 0.f, 0.f, 0.f};
    #pragma unroll
    for (int i = 0; i < 4; ++i)
        #pragma unroll
        for (int j = 0; j < 4; ++j) acc[i][j] = zero;

    const int nkt = Kp >> 6;
    for (int kt = 0; kt < nkt; ++kt) {
        const int k0 = kt << 6;
        // stage A tile (128x64) and B tile (128x64); LDS linear, source
        // pre-swizzled so reads can XOR-swizzle (slot ^= row&7).
        #pragma unroll
        for (int i = 0; i < 4; ++i) {
            const int c = t + i * 256;
            const int row = c >> 3, slot = c & 7;
            const int ss = slot ^ (row & 7);
            async_cp16(A + (size_t)(tm + row) * lda + k0 + ss * 8, &As[c * 8]);
        }
        #pragma unroll
        for (int i = 0; i < 4; ++i) {
            const int c = t + i * 256;
            const int row = c >> 3, slot = c & 7;
            const int ss = slot ^ (row & 7);
            async_cp16(B + (size_t)(tn + row) * ldb + k0 + ss * 8, &Bs[c * 8]);
        }
        __syncthreads();   // compiler drains vmcnt before s_barrier

        #pragma unroll
        for (int ks = 0; ks < 2; ++ks) {
            half8 af[4], bf[4];
            #pragma unroll
            for (int mi = 0; mi < 4; ++mi) {
                const int ra = wm + mi * 16 + lr;
                const int s  = (ks * 4 + lg) ^ (ra & 7);
                af[mi] = *(const half8*)((const char*)As + ra * 128 + s * 16);
            }
            #pragma unroll
            for (int ni = 0; ni < 4; ++ni) {
                const int rb = wn + ni * 16 + lr;
                const int s  = (ks * 4 + lg) ^ (rb & 7);
                bf[ni] = *(const half8*)((const char*)Bs + rb * 128 + s * 16);
            }
            #pragma unroll
            for (int mi = 0; mi < 4; ++mi)
                #pragma unroll
                for (int ni = 0; ni < 4; ++ni)
                    acc[mi][ni] = __builtin_amdgcn_mfma_f32_16x16x32_f16(
                        af[mi], bf[ni], acc[mi][ni], 0, 0, 0);
        }
        __syncthreads();
    }

    // epilogue: D layout col = lane&15, row = 4*(lane>>4)+reg  (m89-verified)
    if (OMODE == 2) {
        float* C = (float*)Call + (size_t)e * cStride;
        #pragma unroll
        for (int mi = 0; mi < 4; ++mi)
            #pragma unroll
            for (int rr = 0; rr < 4; ++rr) {
                const int m = tm + wm + mi * 16 + lg * 4 + rr;
                if (m >= M) continue;
                #pragma unroll
                for (int ni = 0; ni < 4; ++ni) {
                    const int n = tn + wn + ni * 16 + lr;
                    if (n >= Ncols) continue;
                    const float x = acc[mi][ni][rr];
                    C[(size_t)m * ldc + n] = 1.0f / (1.0f + __expf(-x));
                }
            }
    } else {
        _Float16* C = (_Float16*)Call + (size_t)e * cStride;
        #pragma unroll
        for (int mi = 0; mi < 4; ++mi)
            #pragma unroll
            for (int rr = 0; rr < 4; ++rr) {
                const int m = tm + wm + mi * 16 + lg * 4 + rr;
                #pragma unroll
                for (int ni = 0; ni < 4; ++ni) {
                    const int n = tn + wn + ni * 16 + lr;
                    float x = acc[mi][ni][rr];
                    if (ACT) x = tanhf(x);
                    const bool ok = (m < M) && (n < Ncols);
                    const _Float16 hv = ok ? (_Float16)x : (_Float16)0.f;
                    if (OMODE == 0) C[(size_t)m * ldc + n] = hv;
                    else            C[(size_t)n * ldc + m] = hv;
                }
            }
    }
}

// ---------------- launcher ----------------
extern "C" void kernel_launch(void* const* d_in, const int* in_sizes, int n_in,
                              void* d_out, int out_size, void* d_ws, size_t ws_size,
                              hipStream_t stream)
{
    const float* X1 = (const float*)d_in[0];
    const float* X2 = (const float*)d_in[1];

    _Float16* ws = (_Float16*)d_ws;
    size_t off = 0;
    auto alloc = [&](size_t elems) { _Float16* p = ws + off; off += elems; return p; };
    _Float16* Xp  = alloc(2ull * PAD * PAD);
    _Float16* T1  = alloc(4ull * 256 * PAD);
    _Float16* Z1  = alloc(4ull * PAD * 256);
    _Float16* T2  = alloc(4ull * 128 * PAD);
    _Float16* Z2  = alloc(4ull * PAD * 128);
    _Float16* T3  = alloc(4ull * 128 * PAD);
    _Float16* Z3  = alloc(4ull * PAD * 128);
    _Float16* W1t = alloc(4ull * 256 * PAD);
    _Float16* W2t = alloc(4ull * 128 * 256);
    _Float16* W3t = alloc(4ull * 128 * 128);
    _Float16* Adj = (_Float16*)d_out;   // 4 x 3072 x 3072 fp16 = 75.5 MB < 144 MB

    // prep: pad/cast X1,X2 + 4 adjacencies
    Pad6 p6;
    p6.src[0] = X1; p6.dst[0] = Xp;
    p6.src[1] = X2; p6.dst[1] = Xp + (size_t)PAD * PAD;
    for (int i = 0; i < 4; ++i) {
        p6.src[2 + i] = (const float*)d_in[2 + i];
        p6.dst[2 + i] = Adj + (size_t)i * PAD * PAD;
    }
    pad_cast6<<<dim3(4608, 6, 1), 256, 0, stream>>>(p6);

    // prep: transpose/cast 12 weights
    Wt12 w12;
    for (int enc = 0; enc < 4; ++enc) {
        w12.src[enc]     = (const float*)d_in[6 + enc * 3 + 0];
        w12.dst[enc]     = W1t + (size_t)enc * 256 * PAD;
        w12.fi[enc] = MR;  w12.fo[enc] = 256; w12.ldk[enc] = PAD; w12.nr[enc] = 256;

        w12.src[4 + enc] = (const float*)d_in[6 + enc * 3 + 1];
        w12.dst[4 + enc] = W2t + (size_t)enc * 128 * 256;
        w12.fi[4 + enc] = 256; w12.fo[4 + enc] = 128; w12.ldk[4 + enc] = 256; w12.nr[4 + enc] = 128;

        w12.src[8 + enc] = (const float*)d_in[6 + enc * 3 + 2];
        w12.dst[8 + enc] = W3t + (size_t)enc * 128 * 128;
        w12.fi[8 + enc] = 128; w12.fo[8 + enc] = 64; w12.ldk[8 + enc] = 128; w12.nr[8 + enc] = 128;
    }
    wt_cast12<<<dim3(3072, 12, 1), 256, 0, stream>>>(w12);

    const size_t adjStride = (size_t)PAD * PAD;

    // step1: T1 = tanh(Xp @ W1t^T)^T   M=3000 N=256 K=3072
    gemm_bt<1, 1><<<dim3(24, 2, 4), 256, 0, stream>>>(
        Xp, adjStride, 1, W1t, (size_t)256 * PAD, T1, (size_t)256 * PAD,
        MR, 256, PAD, PAD, PAD, PAD);
    // step2: Z1 = Adj @ T1^T           M=3000 N=256 K=3072
    gemm_bt<0, 0><<<dim3(24, 2, 4), 256, 0, stream>>>(
        Adj, adjStride, 3, T1, (size_t)256 * PAD, Z1, (size_t)PAD * 256,
        MR, 256, PAD, PAD, PAD, 256);
    // step3: T2 = tanh(Z1 @ W2t^T)^T   M=3000 N=128 K=256
    gemm_bt<1, 1><<<dim3(24, 1, 4), 256, 0, stream>>>(
        Z1, (size_t)PAD * 256, 3, W2t, (size_t)128 * 256, T2, (size_t)128 * PAD,
        MR, 128, 256, 256, 256, PAD);
    // step4: Z2 = Adj @ T2^T           M=3000 N=128 K=3072
    gemm_bt<0, 0><<<dim3(24, 1, 4), 256, 0, stream>>>(
        Adj, adjStride, 3, T2, (size_t)128 * PAD, Z2, (size_t)PAD * 128,
        MR, 128, PAD, PAD, PAD, 128);
    // step5: T3 = (Z2 @ W3t^T)^T       M=3000 N=64 K=128  (no activation)
    gemm_bt<0, 1><<<dim3(24, 1, 4), 256, 0, stream>>>(
        Z2, (size_t)PAD * 128, 3, W3t, (size_t)128 * 128, T3, (size_t)128 * PAD,
        MR, 64, 128, 128, 128, PAD);
    // step6: Z3 = Adj @ T3^T           M=3000 N=64 K=3072
    gemm_bt<0, 0><<<dim3(24, 1, 4), 256, 0, stream>>>(
        Adj, adjStride, 3, T3, (size_t)128 * PAD, Z3, (size_t)PAD * 128,
        MR, 64, PAD, PAD, PAD, 128);
    // step7: OUT = sigmoid(Z3 @ Z3^T)  M=N=3000 K=64, fp32 to d_out
    gemm_bt<0, 2><<<dim3(24, 24, 4), 256, 0, stream>>>(
        Z3, (size_t)PAD * 128, 3, Z3, (size_t)PAD * 128, d_out, (size_t)9000000,
        MR, MR, 64, 128, 128, MR);
}

// Round 2
// 312.108 us; speedup vs baseline: 1.1285x; 1.1285x over previous
//
#include <hip/hip_runtime.h>
#include <stdint.h>
#include <stddef.h>

// ---------------------------------------------------------------------------
// 4 GAE encoders, fp16 MFMA. All GEMMs: C = A @ B^T (A:[M][lda], B:[N][ldb]).
//   step1: T1[f][n] = tanh-reduce( W1t @ X^T )    (split-K 2, fp32 partials)
//   step2: Z1[n][f] = reduce( Adj @ T1^T )        (split-K 2)
//   step3: T2[g][n] = tanh-reduce( W2t @ Z1^T )   (split-K 2)
//   step4: Z2[n][g] = reduce( Adj @ T2^T )        (split-K 4)
//   step5: T3[h][n] = W3t @ Z2^T                  (direct fp16)
//   step6: Z3[n][h] = reduce( Adj @ T3^T )        (split-K 4)
//   step7: OUT = sigmoid( Z3 @ Z3^T )             (fp32, LDS-repacked stores)
// Adjacency fp16 copies live in d_out (dead before step7 overwrites it).
// X is consumed fp32 directly via reg-staged B path in step1 (no pre-pass).
// ---------------------------------------------------------------------------

typedef __attribute__((ext_vector_type(8))) _Float16 half8;
typedef __attribute__((ext_vector_type(4))) float f32x4;

#define PAD 3072
#define MR  3000
#define ADJ_STRIDE ((size_t)PAD * PAD)

static __device__ __forceinline__ void async_cp16(const _Float16* g, _Float16* l) {
    __builtin_amdgcn_global_load_lds((const __attribute__((address_space(1))) void*)g,
                                     (__attribute__((address_space(3))) void*)l, 16, 0, 0);
}

// ---------------- prep: cast 4 adjacencies fp32->fp16, pad to 3072 ----------
struct Adj4 { const float* src[4]; };

__global__ __launch_bounds__(256) void adj_cast4(Adj4 p, _Float16* __restrict__ dst) {
    const int z   = blockIdx.y;
    const int idx = blockIdx.x * 256 + threadIdx.x;   // 3072*192 units per z
    const int row = idx / 192;
    const int u   = idx - row * 192;
    const int c0  = u * 16;
    const float* sp = p.src[z] + (size_t)row * MR + c0;
    _Float16* d = dst + (size_t)z * ADJ_STRIDE + (size_t)row * PAD + c0;
    half8 h0, h1;
    const bool rok = row < MR;
    if (rok && c0 < MR) {
        f32x4 v0 = __builtin_nontemporal_load((const f32x4*)sp);
        f32x4 v1 = __builtin_nontemporal_load((const f32x4*)(sp + 4));
        #pragma unroll
        for (int j = 0; j < 4; ++j) { h0[j] = (_Float16)v0[j]; h0[4 + j] = (_Float16)v1[j]; }
    } else {
        #pragma unroll
        for (int j = 0; j < 8; ++j) h0[j] = (_Float16)0.f;
    }
    if (rok && c0 + 8 < MR) {
        f32x4 v2 = __builtin_nontemporal_load((const f32x4*)(sp + 8));
        f32x4 v3 = __builtin_nontemporal_load((const f32x4*)(sp + 12));
        #pragma unroll
        for (int j = 0; j < 4; ++j) { h1[j] = (_Float16)v2[j]; h1[4 + j] = (_Float16)v3[j]; }
    } else {
        #pragma unroll
        for (int j = 0; j < 8; ++j) h1[j] = (_Float16)0.f;
    }
    *(half8*)d = h0;
    *(half8*)(d + 8) = h1;
}

// ---------------- prep: weights -> fp16 transposed ----------
struct Wt12 { const float* src[12]; _Float16* dst[12];
              int fi[12]; int fo[12]; int ldk[12]; int nr[12]; };

__global__ __launch_bounds__(256) void wt_cast12(Wt12 p) {
    const int z   = blockIdx.y;
    const int idx = blockIdx.x * 256 + threadIdx.x;
    const int ldk = p.ldk[z];
    if (idx >= p.nr[z] * ldk) return;
    const int r = idx / ldk;          // fan_out index
    const int k = idx - r * ldk;      // fan_in  index
    float v = 0.f;
    if (r < p.fo[z] && k < p.fi[z]) v = p.src[z][(size_t)k * p.fo[z] + r];
    p.dst[z][(size_t)r * ldk + k] = (_Float16)v;
}

// ---------------- GEMM: C = A @ B^T ----------------
// OMODE: 0 = direct fp16 (opt tanh via ACT), 2 = fp32 sigmoid (LDS repack),
//        3 = fp32 raw partial (LDS repack).  S = split-K factor.
// BSRC:  0 = B fp16 via global_load_lds, 1 = B fp32 (X1/X2) reg-staged.
template<int ACT, int OMODE, int S, int BSRC>
__global__ __launch_bounds__(256, 2)
void gemm_bt(const _Float16* __restrict__ Aall, size_t aStride,
             const _Float16* __restrict__ Ball, size_t bStride,
             const float* __restrict__ Bf0, const float* __restrict__ Bf1,
             void* __restrict__ Call, size_t cStride,
             int M, int Ncols, int Kp, int lda, int ldb, int ldc,
             int mBound, int nBound)
{
    __shared__ _Float16 smem[128 * 64 * 2];
    _Float16* As = smem;
    _Float16* Bs = smem + 8192;

    const int z   = blockIdx.z;
    const int e   = z / S;
    const int ksl = z - e * S;
    const int Kslice = Kp / S;
    const int kbase  = ksl * Kslice;

    const _Float16* A = Aall + (size_t)e * aStride;
    const _Float16* B = Ball + (size_t)e * bStride;
    const float*    Bf = (e & 1) ? Bf1 : Bf0;

    const int tm = blockIdx.x * 128;
    const int tn = blockIdx.y * 128;
    const int t    = threadIdx.x;
    const int lane = t & 63;
    const int w    = t >> 6;
    const int wm   = (w >> 1) * 64;
    const int wn   = (w & 1) * 64;
    const int lr   = lane & 15;
    const int lg   = lane >> 4;

    f32x4 acc[4][4];
    const f32x4 zero = {0.f, 0.f, 0.f, 0.f};
    #pragma unroll
    for (int i = 0; i < 4; ++i)
        #pragma unroll
        for (int j = 0; j < 4; ++j) acc[i][j] = zero;

    const int nkt = Kslice >> 6;
    for (int kt = 0; kt < nkt; ++kt) {
        const int k0 = kbase + (kt << 6);
        #pragma unroll
        for (int i = 0; i < 4; ++i) {
            const int c = t + i * 256;
            const int row = c >> 3, slot = c & 7;
            const int ss = slot ^ (row & 7);
            async_cp16(A + (size_t)(tm + row) * lda + k0 + ss * 8, &As[c * 8]);
        }
        if (BSRC) {
            // reg-stage fp32 B (X), bounds-guarded, swizzled ds_write
            #pragma unroll
            for (int i = 0; i < 4; ++i) {
                const int c = t + i * 256;
                const int row = c >> 3, g = c & 7;
                const int grow = tn + row;
                const int gcol = k0 + g * 8;
                half8 h;
                if (grow < MR && gcol < MR) {
                    const float* bp = Bf + (size_t)grow * MR + gcol;
                    f32x4 v0 = *(const f32x4*)bp;
                    f32x4 v1 = *(const f32x4*)(bp + 4);
                    #pragma unroll
                    for (int j = 0; j < 4; ++j) { h[j] = (_Float16)v0[j]; h[4 + j] = (_Float16)v1[j]; }
                } else {
                    #pragma unroll
                    for (int j = 0; j < 8; ++j) h[j] = (_Float16)0.f;
                }
                *(half8*)&Bs[row * 64 + ((g ^ (row & 7)) << 3)] = h;
            }
        } else {
            #pragma unroll
            for (int i = 0; i < 4; ++i) {
                const int c = t + i * 256;
                const int row = c >> 3, slot = c & 7;
                const int ss = slot ^ (row & 7);
                async_cp16(B + (size_t)(tn + row) * ldb + k0 + ss * 8, &Bs[c * 8]);
            }
        }
        __syncthreads();

        #pragma unroll
        for (int ks = 0; ks < 2; ++ks) {
            half8 af[4], bf[4];
            #pragma unroll
            for (int mi = 0; mi < 4; ++mi) {
                const int ra = wm + mi * 16 + lr;
                const int s  = (ks * 4 + lg) ^ (ra & 7);
                af[mi] = *(const half8*)((const char*)As + ra * 128 + s * 16);
            }
            #pragma unroll
            for (int ni = 0; ni < 4; ++ni) {
                const int rb = wn + ni * 16 + lr;
                const int s  = (ks * 4 + lg) ^ (rb & 7);
                bf[ni] = *(const half8*)((const char*)Bs + rb * 128 + s * 16);
            }
            #pragma unroll
            for (int mi = 0; mi < 4; ++mi)
                #pragma unroll
                for (int ni = 0; ni < 4; ++ni)
                    acc[mi][ni] = __builtin_amdgcn_mfma_f32_16x16x32_f16(
                        af[mi], bf[ni], acc[mi][ni], 0, 0, 0);
        }
        __syncthreads();
    }

    // epilogue. D layout: col = lane&15, row = 4*(lane>>4)+reg (m89-verified).
    if (OMODE == 0) {
        _Float16* C = (_Float16*)Call + (size_t)e * cStride;
        #pragma unroll
        for (int mi = 0; mi < 4; ++mi)
            #pragma unroll
            for (int rr = 0; rr < 4; ++rr) {
                const int m = tm + wm + mi * 16 + lg * 4 + rr;
                #pragma unroll
                for (int ni = 0; ni < 4; ++ni) {
                    const int n = tn + wn + ni * 16 + lr;
                    float x = acc[mi][ni][rr];
                    if (ACT) x = tanhf(x);
                    const bool ok = (m < M) && (n < Ncols);
                    C[(size_t)m * ldc + n] = ok ? (_Float16)x : (_Float16)0.f;
                }
            }
    } else {
        // fp32 LDS-repack epilogue: per-wave 32x64 staging, float4 stores.
        float* Cp = (float*)Call +
                    (size_t)(OMODE == 3 ? z : e) * cStride;
        float* ep = (float*)smem + w * 2048;   // 32 rows x 64 cols
        #pragma unroll
        for (int hs = 0; hs < 2; ++hs) {
            __syncthreads();
            #pragma unroll
            for (int mi2 = 0; mi2 < 2; ++mi2)
                #pragma unroll
                for (int ni = 0; ni < 4; ++ni)
                    #pragma unroll
                    for (int rr = 0; rr < 4; ++rr) {
                        const int row = mi2 * 16 + lg * 4 + rr;
                        const int col = ni * 16 + lr;
                        const int sw  = (((row ^ (row >> 2)) & 3) << 4);
                        ep[row * 64 + (col ^ sw)] = acc[hs * 2 + mi2][ni][rr];
                    }
            __syncthreads();
            #pragma unroll
            for (int r2 = 0; r2 < 8; ++r2) {
                const int row = r2 * 4 + (lane >> 4);
                const int c4  = (lane & 15) * 4;
                const int sw  = (((row ^ (row >> 2)) & 3) << 4);
                f32x4 v = *(const f32x4*)&ep[row * 64 + (c4 ^ sw)];
                const int gm = tm + wm + hs * 32 + row;
                const int gn = tn + wn + c4;
                if (gm < mBound && gn < nBound) {
                    if (OMODE == 2) {
                        #pragma unroll
                        for (int j = 0; j < 4; ++j)
                            v[j] = 1.0f / (1.0f + __expf(-v[j]));
                    }
                    *(f32x4*)&Cp[(size_t)gm * ldc + gn] = v;
                }
            }
        }
    }
}

// ---------------- split-K reduce: out = act(sum_s P[s]) in fp16 ----------
template<int ACT, int S>
__global__ __launch_bounds__(256)
void reduce_k(const float* __restrict__ P, _Float16* __restrict__ out, size_t region)
{
    const size_t e    = blockIdx.y;
    const size_t base = (size_t)(blockIdx.x * 256 + threadIdx.x) * 8;
    const float* p0 = P + e * S * region + base;
    f32x4 s0 = {0.f, 0.f, 0.f, 0.f}, s1 = s0;
    #pragma unroll
    for (int s = 0; s < S; ++s) {
        const float* p = p0 + (size_t)s * region;
        s0 += *(const f32x4*)p;
        s1 += *(const f32x4*)(p + 4);
    }
    half8 h;
    #pragma unroll
    for (int j = 0; j < 8; ++j) {
        float x = (j < 4) ? s0[j] : s1[j - 4];
        if (ACT) x = tanhf(x);
        h[j] = (_Float16)x;
    }
    *(half8*)(out + e * region + base) = h;
}

// ---------------- launcher ----------------
extern "C" void kernel_launch(void* const* d_in, const int* in_sizes, int n_in,
                              void* d_out, int out_size, void* d_ws, size_t ws_size,
                              hipStream_t stream)
{
    const float* X1 = (const float*)d_in[0];
    const float* X2 = (const float*)d_in[1];

    const size_t R1 = 786432;   // 256*3072 and 3072*256
    const size_t R2 = 393216;   // 128*3072 and 3072*128

    float* Part = (float*)d_ws;                       // 16 * 393216 = 8 * 786432 floats
    _Float16* hb = (_Float16*)(Part + 16 * R2);
    size_t off = 0;
    auto alloc = [&](size_t elems) { _Float16* p = hb + off; off += elems; return p; };
    _Float16* T1  = alloc(4 * R1);
    _Float16* Z1  = alloc(4 * R1);
    _Float16* T2  = alloc(4 * R2);
    _Float16* Z2  = alloc(4 * R2);
    _Float16* T3  = alloc(4 * R2);
    _Float16* Z3  = alloc(4 * R2);
    _Float16* W1t = alloc(4ull * 256 * PAD);
    _Float16* W2t = alloc(4ull * 128 * 256);
    _Float16* W3t = alloc(4ull * 128 * 128);
    _Float16* Adj = (_Float16*)d_out;   // 4 x 3072 x 3072 fp16 = 75.5 MB < 144 MB

    // prep: adjacencies fp32 -> padded fp16
    Adj4 a4;
    for (int i = 0; i < 4; ++i) a4.src[i] = (const float*)d_in[2 + i];
    adj_cast4<<<dim3(2304, 4, 1), 256, 0, stream>>>(a4, Adj);

    // prep: weights -> fp16 transposed
    Wt12 w12;
    for (int enc = 0; enc < 4; ++enc) {
        w12.src[enc]     = (const float*)d_in[6 + enc * 3 + 0];
        w12.dst[enc]     = W1t + (size_t)enc * 256 * PAD;
        w12.fi[enc] = MR;  w12.fo[enc] = 256; w12.ldk[enc] = PAD; w12.nr[enc] = 256;

        w12.src[4 + enc] = (const float*)d_in[6 + enc * 3 + 1];
        w12.dst[4 + enc] = W2t + (size_t)enc * 128 * 256;
        w12.fi[4 + enc] = 256; w12.fo[4 + enc] = 128; w12.ldk[4 + enc] = 256; w12.nr[4 + enc] = 128;

        w12.src[8 + enc] = (const float*)d_in[6 + enc * 3 + 2];
        w12.dst[8 + enc] = W3t + (size_t)enc * 128 * 128;
        w12.fi[8 + enc] = 128; w12.fo[8 + enc] = 64; w12.ldk[8 + enc] = 128; w12.nr[8 + enc] = 128;
    }
    wt_cast12<<<dim3(3072, 12, 1), 256, 0, stream>>>(w12);

    const int BIG = 1 << 30;

    // step1: P = W1t @ X^T   M=256 N=3072 K=3072, split-K 2, B = fp32 X
    gemm_bt<0, 3, 2, 1><<<dim3(2, 24, 8), 256, 0, stream>>>(
        W1t, (size_t)256 * PAD, nullptr, 0, X1, X2,
        Part, R1, 256, PAD, PAD, PAD, MR, PAD, BIG, BIG);
    reduce_k<1, 2><<<dim3(384, 4, 1), 256, 0, stream>>>(Part, T1, R1);

    // step2: P = Adj @ T1^T  M=3072 N=256 K=3072, split-K 2
    gemm_bt<0, 3, 2, 0><<<dim3(24, 2, 8), 256, 0, stream>>>(
        Adj, ADJ_STRIDE, T1, R1, nullptr, nullptr,
        Part, R1, PAD, 256, PAD, PAD, PAD, 256, BIG, BIG);
    reduce_k<0, 2><<<dim3(384, 4, 1), 256, 0, stream>>>(Part, Z1, R1);

    // step3: P = W2t @ Z1^T  M=128 N=3072 K=256, split-K 2
    gemm_bt<0, 3, 2, 0><<<dim3(1, 24, 8), 256, 0, stream>>>(
        W2t, (size_t)128 * 256, Z1, R1, nullptr, nullptr,
        Part, R2, 128, PAD, 256, 256, 256, PAD, BIG, BIG);
    reduce_k<1, 2><<<dim3(192, 4, 1), 256, 0, stream>>>(Part, T2, R2);

    // step4: P = Adj @ T2^T  M=3072 N=128 K=3072, split-K 4
    gemm_bt<0, 3, 4, 0><<<dim3(24, 1, 16), 256, 0, stream>>>(
        Adj, ADJ_STRIDE, T2, R2, nullptr, nullptr,
        Part, R2, PAD, 128, PAD, PAD, PAD, 128, BIG, BIG);
    reduce_k<0, 4><<<dim3(192, 4, 1), 256, 0, stream>>>(Part, Z2, R2);

    // step5: T3 = W3t @ Z2^T  M=128 N=3072 K=128, direct fp16
    gemm_bt<0, 0, 1, 0><<<dim3(1, 24, 4), 256, 0, stream>>>(
        W3t, (size_t)128 * 128, Z2, R2, nullptr, nullptr,
        T3, R2, 128, PAD, 128, 128, 128, PAD, BIG, BIG);

    // step6: P = Adj @ T3^T  M=3072 N=128 K=3072, split-K 4
    gemm_bt<0, 3, 4, 0><<<dim3(24, 1, 16), 256, 0, stream>>>(
        Adj, ADJ_STRIDE, T3, R2, nullptr, nullptr,
        Part, R2, PAD, 128, PAD, PAD, PAD, 128, BIG, BIG);
    reduce_k<0, 4><<<dim3(192, 4, 1), 256, 0, stream>>>(Part, Z3, R2);

    // step7: OUT = sigmoid(Z3 @ Z3^T)  M=N=3000 K=128, fp32 to d_out
    gemm_bt<0, 2, 1, 0><<<dim3(24, 24, 4), 256, 0, stream>>>(
        Z3, R2, Z3, R2, nullptr, nullptr,
        d_out, (size_t)MR * MR, MR, MR, 128, 128, 128, MR, MR, MR);
}

// Round 3
// 274.379 us; speedup vs baseline: 1.2837x; 1.1375x over previous
//
#include <hip/hip_runtime.h>
#include <stdint.h>
#include <stddef.h>

// ---------------------------------------------------------------------------
// 4 GAE encoders, fp16 MFMA. All GEMMs: C = A @ B^T (A:[M][lda], B:[N][ldb]).
//   fused : adjacency fp32->fp16 cast  ∥  step1 P = W1t @ X^T (split-K 4)
//   step2 : Z1 = reduce( Adj @ T1^T )          (split-K 4)
//   step3 : T2 = tanh-reduce( W2t @ Z1^T )     (split-K 2)
//   step4 : Z2 = reduce( Adj @ T2^T )          (split-K 8)
//   step5 : T3 = W3t @ Z2^T                    (direct fp16)
//   step6 : Z3 = reduce( Adj @ T3^T )          (split-K 8)
//   step7 : OUT = sigmoid( Z3 @ Z3^T ), K=64   (fp32, LDS-repacked stores)
// Adj fp16 copies AND the fp32 split-K partial buffer live in d_out
// (75.5 MB + 50.3 MB < 144 MB; both dead before step7 overwrites d_out).
// ---------------------------------------------------------------------------

typedef __attribute__((ext_vector_type(8))) _Float16 half8;
typedef __attribute__((ext_vector_type(4))) float f32x4;

#define PAD 3072
#define MR  3000
#define ADJ_STRIDE ((size_t)PAD * PAD)

static __device__ __forceinline__ void async_cp16(const _Float16* g, _Float16* l) {
    __builtin_amdgcn_global_load_lds((const __attribute__((address_space(1))) void*)g,
                                     (__attribute__((address_space(3))) void*)l, 16, 0, 0);
}

// ---------------- prep: weights -> fp16 transposed ----------
struct Wt12 { const float* src[12]; _Float16* dst[12];
              int fi[12]; int fo[12]; int ldk[12]; int nr[12]; };

__global__ __launch_bounds__(256) void wt_cast12(Wt12 p) {
    const int z   = blockIdx.y;
    const int idx = blockIdx.x * 256 + threadIdx.x;
    const int ldk = p.ldk[z];
    if (idx >= p.nr[z] * ldk) return;
    const int r = idx / ldk;          // fan_out index
    const int k = idx - r * ldk;      // fan_in  index
    float v = 0.f;
    if (r < p.fo[z] && k < p.fi[z]) v = p.src[z][(size_t)k * p.fo[z] + r];
    p.dst[z][(size_t)r * ldk + k] = (_Float16)v;
}

// ---------------- GEMM body: C = A @ B^T ----------------
struct GArgs {
    const _Float16* Aall; size_t aStride;
    const _Float16* Ball; size_t bStride;
    const float* Bf0; const float* Bf1;
    void* Call; size_t cStride;
    int M, Ncols, Kp, lda, ldb, ldc, mBound, nBound;
};

// OMODE: 0 = direct fp16 (opt tanh via ACT), 2 = fp32 sigmoid (LDS repack),
//        3 = fp32 raw partial (LDS repack).  S = split-K factor.
// BSRC:  0 = B fp16 via global_load_lds, 1 = B fp32 (X1/X2) reg-staged.
template<int ACT, int OMODE, int S, int BSRC>
static __device__ __forceinline__
void gemm_body(const GArgs& ga, int bx, int by, int bz, _Float16* smem)
{
    _Float16* As = smem;
    _Float16* Bs = smem + 8192;

    const int z   = bz;
    const int e   = z / S;
    const int ksl = z - e * S;
    const int Kslice = ga.Kp / S;
    const int kbase  = ksl * Kslice;

    const _Float16* A = ga.Aall + (size_t)e * ga.aStride;
    const _Float16* B = ga.Ball + (size_t)e * ga.bStride;
    const float*    Bf = (e & 1) ? ga.Bf1 : ga.Bf0;

    const int tm = bx * 128;
    const int tn = by * 128;
    const int t    = threadIdx.x;
    const int lane = t & 63;
    const int w    = t >> 6;
    const int wm   = (w >> 1) * 64;
    const int wn   = (w & 1) * 64;
    const int lr   = lane & 15;
    const int lg   = lane >> 4;

    f32x4 acc[4][4];
    const f32x4 zero = {0.f, 0.f, 0.f, 0.f};
    #pragma unroll
    for (int i = 0; i < 4; ++i)
        #pragma unroll
        for (int j = 0; j < 4; ++j) acc[i][j] = zero;

    const int nkt = Kslice >> 6;
    for (int kt = 0; kt < nkt; ++kt) {
        const int k0 = kbase + (kt << 6);
        #pragma unroll
        for (int i = 0; i < 4; ++i) {
            const int c = t + i * 256;
            const int row = c >> 3, slot = c & 7;
            const int ss = slot ^ (row & 7);
            async_cp16(A + (size_t)(tm + row) * ga.lda + k0 + ss * 8, &As[c * 8]);
        }
        if (BSRC) {
            // reg-stage fp32 B (X), bounds-guarded, swizzled ds_write
            #pragma unroll
            for (int i = 0; i < 4; ++i) {
                const int c = t + i * 256;
                const int row = c >> 3, g = c & 7;
                const int grow = tn + row;
                const int gcol = k0 + g * 8;
                half8 h;
                if (grow < MR && gcol < MR) {
                    const float* bp = Bf + (size_t)grow * MR + gcol;
                    f32x4 v0 = *(const f32x4*)bp;
                    f32x4 v1 = *(const f32x4*)(bp + 4);
                    #pragma unroll
                    for (int j = 0; j < 4; ++j) { h[j] = (_Float16)v0[j]; h[4 + j] = (_Float16)v1[j]; }
                } else {
                    #pragma unroll
                    for (int j = 0; j < 8; ++j) h[j] = (_Float16)0.f;
                }
                *(half8*)&Bs[row * 64 + ((g ^ (row & 7)) << 3)] = h;
            }
        } else {
            #pragma unroll
            for (int i = 0; i < 4; ++i) {
                const int c = t + i * 256;
                const int row = c >> 3, slot = c & 7;
                const int ss = slot ^ (row & 7);
                async_cp16(B + (size_t)(tn + row) * ga.ldb + k0 + ss * 8, &Bs[c * 8]);
            }
        }
        __syncthreads();

        #pragma unroll
        for (int ks = 0; ks < 2; ++ks) {
            half8 af[4], bf[4];
            #pragma unroll
            for (int mi = 0; mi < 4; ++mi) {
                const int ra = wm + mi * 16 + lr;
                const int s  = (ks * 4 + lg) ^ (ra & 7);
                af[mi] = *(const half8*)((const char*)As + ra * 128 + s * 16);
            }
            #pragma unroll
            for (int ni = 0; ni < 4; ++ni) {
                const int rb = wn + ni * 16 + lr;
                const int s  = (ks * 4 + lg) ^ (rb & 7);
                bf[ni] = *(const half8*)((const char*)Bs + rb * 128 + s * 16);
            }
            #pragma unroll
            for (int mi = 0; mi < 4; ++mi)
                #pragma unroll
                for (int ni = 0; ni < 4; ++ni)
                    acc[mi][ni] = __builtin_amdgcn_mfma_f32_16x16x32_f16(
                        af[mi], bf[ni], acc[mi][ni], 0, 0, 0);
        }
        __syncthreads();
    }

    // epilogue. D layout: col = lane&15, row = 4*(lane>>4)+reg (m89-verified).
    if (OMODE == 0) {
        _Float16* C = (_Float16*)ga.Call + (size_t)e * ga.cStride;
        #pragma unroll
        for (int mi = 0; mi < 4; ++mi)
            #pragma unroll
            for (int rr = 0; rr < 4; ++rr) {
                const int m = tm + wm + mi * 16 + lg * 4 + rr;
                #pragma unroll
                for (int ni = 0; ni < 4; ++ni) {
                    const int n = tn + wn + ni * 16 + lr;
                    float x = acc[mi][ni][rr];
                    if (ACT) x = tanhf(x);
                    const bool ok = (m < ga.M) && (n < ga.Ncols);
                    C[(size_t)m * ga.ldc + n] = ok ? (_Float16)x : (_Float16)0.f;
                }
            }
    } else {
        // fp32 LDS-repack epilogue: per-wave 32x64 staging, float4 stores.
        float* Cp = (float*)ga.Call + (size_t)(OMODE == 3 ? z : e) * ga.cStride;
        float* ep = (float*)smem + w * 2048;   // 32 rows x 64 cols
        #pragma unroll
        for (int hs = 0; hs < 2; ++hs) {
            __syncthreads();
            #pragma unroll
            for (int mi2 = 0; mi2 < 2; ++mi2)
                #pragma unroll
                for (int ni = 0; ni < 4; ++ni)
                    #pragma unroll
                    for (int rr = 0; rr < 4; ++rr) {
                        const int row = mi2 * 16 + lg * 4 + rr;
                        const int col = ni * 16 + lr;
                        const int sw  = (((row ^ (row >> 2)) & 3) << 4);
                        ep[row * 64 + (col ^ sw)] = acc[hs * 2 + mi2][ni][rr];
                    }
            __syncthreads();
            #pragma unroll
            for (int r2 = 0; r2 < 8; ++r2) {
                const int row = r2 * 4 + (lane >> 4);
                const int c4  = (lane & 15) * 4;
                const int sw  = (((row ^ (row >> 2)) & 3) << 4);
                f32x4 v = *(const f32x4*)&ep[row * 64 + (c4 ^ sw)];
                const int gm = tm + wm + hs * 32 + row;
                const int gn = tn + wn + c4;
                if (gm < ga.mBound && gn < ga.nBound) {
                    if (OMODE == 2) {
                        #pragma unroll
                        for (int j = 0; j < 4; ++j)
                            v[j] = 1.0f / (1.0f + __expf(-v[j]));
                    }
                    *(f32x4*)&Cp[(size_t)gm * ga.ldc + gn] = v;
                }
            }
        }
    }
}

template<int ACT, int OMODE, int S, int BSRC>
__global__ __launch_bounds__(256, 2)
void gemm_bt(GArgs ga) {
    __shared__ _Float16 smem[16384];
    gemm_body<ACT, OMODE, S, BSRC>(ga, blockIdx.x, blockIdx.y, blockIdx.z, smem);
}

// ---------------- fused: step1 GEMM (768 blocks) + adjacency cast ----------
struct Adj4 { const float* src[4]; };

__global__ __launch_bounds__(256, 2)
void fused_s1(GArgs ga, Adj4 a4, _Float16* __restrict__ adst)
{
    __shared__ _Float16 smem[16384];
    const int b = blockIdx.x;
    if (b < 768) {
        const int bz = b & 15;
        const int r  = b >> 4;
        gemm_body<0, 3, 4, 1>(ga, r & 1, r >> 1, bz, smem);
    } else {
        const int cb  = b - 768;
        const int zz  = cb / 2304;
        const int idx = (cb - zz * 2304) * 256 + threadIdx.x;
        const int row = idx / 192;
        const int u   = idx - row * 192;
        const int c0  = u * 16;
        const float* sp = a4.src[zz] + (size_t)row * MR + c0;
        _Float16* d = adst + (size_t)zz * ADJ_STRIDE + (size_t)row * PAD + c0;
        half8 h0, h1;
        const bool rok = row < MR;
        if (rok && c0 < MR) {
            f32x4 v0 = __builtin_nontemporal_load((const f32x4*)sp);
            f32x4 v1 = __builtin_nontemporal_load((const f32x4*)(sp + 4));
            #pragma unroll
            for (int j = 0; j < 4; ++j) { h0[j] = (_Float16)v0[j]; h0[4 + j] = (_Float16)v1[j]; }
        } else {
            #pragma unroll
            for (int j = 0; j < 8; ++j) h0[j] = (_Float16)0.f;
        }
        if (rok && c0 + 8 < MR) {
            f32x4 v2 = __builtin_nontemporal_load((const f32x4*)(sp + 8));
            f32x4 v3 = __builtin_nontemporal_load((const f32x4*)(sp + 12));
            #pragma unroll
            for (int j = 0; j < 4; ++j) { h1[j] = (_Float16)v2[j]; h1[4 + j] = (_Float16)v3[j]; }
        } else {
            #pragma unroll
            for (int j = 0; j < 8; ++j) h1[j] = (_Float16)0.f;
        }
        *(half8*)d = h0;
        *(half8*)(d + 8) = h1;
    }
}

// ---------------- split-K reduce: out = act(sum_s P[s]) in fp16 ----------
template<int ACT, int S>
__global__ __launch_bounds__(256)
void reduce_k(const float* __restrict__ P, _Float16* __restrict__ out, size_t region)
{
    const size_t e    = blockIdx.y;
    const size_t base = (size_t)(blockIdx.x * 256 + threadIdx.x) * 8;
    const float* p0 = P + e * S * region + base;
    f32x4 s0 = {0.f, 0.f, 0.f, 0.f}, s1 = s0;
    #pragma unroll
    for (int s = 0; s < S; ++s) {
        const float* p = p0 + (size_t)s * region;
        s0 += *(const f32x4*)p;
        s1 += *(const f32x4*)(p + 4);
    }
    half8 h;
    #pragma unroll
    for (int j = 0; j < 8; ++j) {
        float x = (j < 4) ? s0[j] : s1[j - 4];
        if (ACT) x = tanhf(x);
        h[j] = (_Float16)x;
    }
    *(half8*)(out + e * region + base) = h;
}

// ---------------- launcher ----------------
extern "C" void kernel_launch(void* const* d_in, const int* in_sizes, int n_in,
                              void* d_out, int out_size, void* d_ws, size_t ws_size,
                              hipStream_t stream)
{
    const float* X1 = (const float*)d_in[0];
    const float* X2 = (const float*)d_in[1];

    const size_t R1 = 786432;   // 256*3072 and 3072*256
    const size_t R2 = 393216;   // 128*3072 and 3072*128

    // d_out layout: [4 x fp16 Adj (75.5 MB)] [fp32 Part (up to 50.3 MB)]
    _Float16* Adj  = (_Float16*)d_out;
    float*    Part = (float*)(Adj + 4 * ADJ_STRIDE);

    _Float16* hb = (_Float16*)d_ws;
    size_t off = 0;
    auto alloc = [&](size_t elems) { _Float16* p = hb + off; off += elems; return p; };
    _Float16* T1  = alloc(4 * R1);
    _Float16* Z1  = alloc(4 * R1);
    _Float16* T2  = alloc(4 * R2);
    _Float16* Z2  = alloc(4 * R2);
    _Float16* T3  = alloc(4 * R2);
    _Float16* Z3  = alloc(4 * R2);
    _Float16* W1t = alloc(4ull * 256 * PAD);
    _Float16* W2t = alloc(4ull * 128 * 256);
    _Float16* W3t = alloc(4ull * 128 * 128);

    // prep: weights -> fp16 transposed (must precede fused step1)
    Wt12 w12;
    for (int enc = 0; enc < 4; ++enc) {
        w12.src[enc]     = (const float*)d_in[6 + enc * 3 + 0];
        w12.dst[enc]     = W1t + (size_t)enc * 256 * PAD;
        w12.fi[enc] = MR;  w12.fo[enc] = 256; w12.ldk[enc] = PAD; w12.nr[enc] = 256;

        w12.src[4 + enc] = (const float*)d_in[6 + enc * 3 + 1];
        w12.dst[4 + enc] = W2t + (size_t)enc * 128 * 256;
        w12.fi[4 + enc] = 256; w12.fo[4 + enc] = 128; w12.ldk[4 + enc] = 256; w12.nr[4 + enc] = 128;

        w12.src[8 + enc] = (const float*)d_in[6 + enc * 3 + 2];
        w12.dst[8 + enc] = W3t + (size_t)enc * 128 * 128;
        w12.fi[8 + enc] = 128; w12.fo[8 + enc] = 64; w12.ldk[8 + enc] = 128; w12.nr[8 + enc] = 128;
    }
    wt_cast12<<<dim3(3072, 12, 1), 256, 0, stream>>>(w12);

    const int BIG = 1 << 30;

    // fused: step1 P = W1t @ X^T (M=256 N=3072 K=3072, S=4, B=fp32 X)
    //        + adjacency fp32->fp16 cast (9216 blocks)
    GArgs g1 = { W1t, (size_t)256 * PAD, nullptr, 0, X1, X2,
                 Part, R1, 256, PAD, PAD, PAD, MR, PAD, BIG, BIG };
    Adj4 a4;
    for (int i = 0; i < 4; ++i) a4.src[i] = (const float*)d_in[2 + i];
    fused_s1<<<dim3(9984, 1, 1), 256, 0, stream>>>(g1, a4, Adj);
    reduce_k<1, 4><<<dim3(384, 4, 1), 256, 0, stream>>>(Part, T1, R1);

    // step2: P = Adj @ T1^T  M=3072 N=256 K=3072, S=4
    GArgs g2 = { Adj, ADJ_STRIDE, T1, R1, nullptr, nullptr,
                 Part, R1, PAD, 256, PAD, PAD, PAD, 256, BIG, BIG };
    gemm_bt<0, 3, 4, 0><<<dim3(24, 2, 16), 256, 0, stream>>>(g2);
    reduce_k<0, 4><<<dim3(384, 4, 1), 256, 0, stream>>>(Part, Z1, R1);

    // step3: P = W2t @ Z1^T  M=128 N=3072 K=256, S=2
    GArgs g3 = { W2t, (size_t)128 * 256, Z1, R1, nullptr, nullptr,
                 Part, R2, 128, PAD, 256, 256, 256, PAD, BIG, BIG };
    gemm_bt<0, 3, 2, 0><<<dim3(1, 24, 8), 256, 0, stream>>>(g3);
    reduce_k<1, 2><<<dim3(192, 4, 1), 256, 0, stream>>>(Part, T2, R2);

    // step4: P = Adj @ T2^T  M=3072 N=128 K=3072, S=8
    GArgs g4 = { Adj, ADJ_STRIDE, T2, R2, nullptr, nullptr,
                 Part, R2, PAD, 128, PAD, PAD, PAD, 128, BIG, BIG };
    gemm_bt<0, 3, 8, 0><<<dim3(24, 1, 32), 256, 0, stream>>>(g4);
    reduce_k<0, 8><<<dim3(192, 4, 1), 256, 0, stream>>>(Part, Z2, R2);

    // step5: T3 = W3t @ Z2^T  M=128 N=3072 K=128, direct fp16
    GArgs g5 = { W3t, (size_t)128 * 128, Z2, R2, nullptr, nullptr,
                 T3, R2, 128, PAD, 128, 128, 128, PAD, BIG, BIG };
    gemm_bt<0, 0, 1, 0><<<dim3(1, 24, 4), 256, 0, stream>>>(g5);

    // step6: P = Adj @ T3^T  M=3072 N=128 K=3072, S=8
    GArgs g6 = { Adj, ADJ_STRIDE, T3, R2, nullptr, nullptr,
                 Part, R2, PAD, 128, PAD, PAD, PAD, 128, BIG, BIG };
    gemm_bt<0, 3, 8, 0><<<dim3(24, 1, 32), 256, 0, stream>>>(g6);
    reduce_k<0, 8><<<dim3(192, 4, 1), 256, 0, stream>>>(Part, Z3, R2);

    // step7: OUT = sigmoid(Z3 @ Z3^T)  M=N=3000 K=64 (cols 64..127 of Z3 zero)
    GArgs g7 = { Z3, R2, Z3, R2, nullptr, nullptr,
                 d_out, (size_t)MR * MR, MR, MR, 64, 128, 128, MR, MR, MR };
    gemm_bt<0, 2, 1, 0><<<dim3(24, 24, 4), 256, 0, stream>>>(g7);
}